// Round 2
// baseline (6017.228 us; speedup 1.0000x reference)
//
#include <hip/hip_runtime.h>

// ---------------------------------------------------------------------------
// VanillaCRF forward on MI355X — R2: persistent cooperative kernel.
// kp layout: elem(row r, col k) at base[((k>>3)*R + r)*8 + (k&7)].
// Frags (m89/m91): A[m=lane&15][k=quad*8+j], B[k=quad*8+j][n=lane&15],
// D[row=quad*4+reg][col=lane&15].
// ---------------------------------------------------------------------------

typedef short v8s __attribute__((ext_vector_type(8)));
typedef float v4f __attribute__((ext_vector_type(4)));
typedef unsigned short u16;

#define MFMA(a, b, c) __builtin_amdgcn_mfma_f32_16x16x32_bf16((a), (b), (c), 0, 0, 0)

static constexpr size_t WMAT    = (size_t)96 * 3072 * 8;
static constexpr size_t SLOT64  = (size_t)96 * 64 * 8;
static constexpr size_t SLOT16  = (size_t)96 * 16 * 8;
static constexpr size_t SLOT128 = (size_t)96 * 128 * 8;

static constexpr size_t OFF_CTR  = 0;
static constexpr size_t SZ_CTR   = 4096;
static constexpr size_t OFF_EM   = OFF_CTR + SZ_CTR;
static constexpr size_t SZ_EM    = (size_t)2 * 64 * 128 * 2 * 4;
static constexpr size_t OFF_XW0  = OFF_EM + SZ_EM;
static constexpr size_t SZ_XW    = (size_t)4 * 128 * 3072 * 4;
static constexpr size_t OFF_XW1  = OFF_XW0 + SZ_XW;
static constexpr size_t OFF_SEQ  = OFF_XW1 + SZ_XW;
static constexpr size_t SZ_SEQ   = (size_t)96 * 128 * 8 * 2;
static constexpr size_t OFF_LABS = OFF_SEQ + SZ_SEQ;
static constexpr size_t SZ_LABS  = 512;
static constexpr size_t OFF_W0   = OFF_LABS + SZ_LABS;
static constexpr size_t SZ_W4    = (size_t)4 * WMAT * 2;
static constexpr size_t OFF_W1X  = OFF_W0 + SZ_W4;
static constexpr size_t OFF_W1R  = OFF_W1X + SZ_W4;
static constexpr size_t OFF_F0   = OFF_W1R + SZ_W4;
static constexpr size_t SZ_F0    = (size_t)2 * 129 * SLOT16 * 2;
static constexpr size_t OFF_H0F  = OFF_F0 + SZ_F0;
static constexpr size_t SZ_H0F   = (size_t)2 * SLOT128 * 2;
static constexpr size_t OFF_B0   = OFF_H0F + SZ_H0F;
static constexpr size_t SZ_S64   = (size_t)2 * 129 * SLOT64 * 2;
static constexpr size_t OFF_F1   = OFF_B0 + SZ_S64;
static constexpr size_t OFF_B1   = OFF_F1 + SZ_S64;
static constexpr size_t WS_NEED  = OFF_B1 + SZ_S64;   // ~145 MB

static constexpr unsigned LDS_BYTES = 147456;          // 96 KB resident + 48 KB stage

static __device__ __forceinline__ u16 f2b(float f) {
  unsigned int u = __float_as_uint(f);
  unsigned int r = (u + 0x7FFFu + ((u >> 16) & 1u)) >> 16;
  return (u16)r;
}
static __device__ __forceinline__ float b2f(u16 u) {
  return __uint_as_float(((unsigned int)u) << 16);
}
static __device__ __forceinline__ float sigf(float x) { return 1.0f / (1.0f + __expf(-x)); }
static __device__ __forceinline__ float tanhfast(float x) {
  return 1.0f - 2.0f / (__expf(2.0f * x) + 1.0f);
}
static __device__ __forceinline__ float lse2(float a, float b) {
  float mx = fmaxf(a, b);
  return mx + __logf(__expf(a - mx) + __expf(b - mx));
}

// group barrier: counter monotonic; target = epoch * nblocks. release-on-arrive,
// acquire-on-spin (agent scope handles cross-XCD L2).
static __device__ __forceinline__ void gbar(unsigned* ctr, unsigned target) {
  __syncthreads();   // drains vmcnt -> all block stores in L2 before arrive
  if (threadIdx.x == 0) {
    __hip_atomic_fetch_add(ctr, 1u, __ATOMIC_RELEASE, __HIP_MEMORY_SCOPE_AGENT);
    while (__hip_atomic_load(ctr, __ATOMIC_ACQUIRE, __HIP_MEMORY_SCOPE_AGENT) < target)
      __builtin_amdgcn_s_sleep(1);
  }
  __syncthreads();
}

// ---------------------------------------------------------------------------
__global__ void init_zero(u16* f0a, u16* f0b, u16* b0a, u16* b0b,
                          u16* f1a, u16* f1b, u16* b1a, u16* b1b, unsigned* ctrs) {
  int idx = blockIdx.x * 256 + threadIdx.x;   // grid 192 -> 49152 == SLOT64
  if (idx < 1024) ctrs[idx] = 0;
  if (idx < (int)SLOT16) { f0a[idx] = 0; f0b[idx] = 0; }
  b0a[idx] = 0; b0b[idx] = 0;
  f1a[idx] = 0; f1b[idx] = 0;
  b1a[idx] = 0; b1b[idx] = 0;
}

__global__ void build_seq(const float* user, const float* sysr, const int* ulab,
                          const int* slab, u16* seqkp, int* labs) {
  int idx = blockIdx.x * 256 + threadIdx.x;   // grid 384
  int t = idx / 768;
  int hh = idx - t * 768;
  float v = (t & 1) ? sysr[(t >> 1) * 768 + hh] : user[(t >> 1) * 768 + hh];
  seqkp[((size_t)(hh >> 3) * 128 + t) * 8 + (hh & 7)] = f2b(v);
  if (idx < 128) labs[idx] = (idx & 1) ? slab[idx >> 1] : ulab[idx >> 1];
}

// 12 matrices -> kp bf16: grp0 Whh0, grp1 Wih1[:,768:], grp2 Whh1
__global__ void cvt_w(const float* postWhh0, const float* priWhh0,
                      const float* postWih1, const float* priWih1,
                      const float* postWhh1, const float* priWhh1,
                      u16* W0kp, u16* W1xkp, u16* W1rkp) {
  int mat = blockIdx.y;
  int grp = mat >> 2;
  int sub = mat & 3;
  int m = sub >> 1;
  int dirw = sub & 1;
  const float* src;
  int stride, coff;
  u16* dstb;
  if (grp == 0)      { src = m ? priWhh0 : postWhh0; stride = 768;  coff = 0;   dstb = W0kp; }
  else if (grp == 1) { src = m ? priWih1 : postWih1; stride = 1536; coff = 768; dstb = W1xkp; }
  else               { src = m ? priWhh1 : postWhh1; stride = 768;  coff = 0;   dstb = W1rkp; }
  src += (size_t)dirw * 3072 * stride;
  int cid = blockIdx.x * 256 + threadIdx.x;   // grid.x = 1152
  int g = cid / 96;
  int kb = cid - g * 96;
  const float* s = src + (size_t)g * stride + coff + (size_t)kb * 8;
  union { u16 h[8]; int4 v; } u;
#pragma unroll
  for (int j = 0; j < 8; ++j) u.h[j] = f2b(s[j]);
  ((int4*)(dstb + (size_t)sub * WMAT))[(size_t)kb * 3072 + g] = u.v;
}

// out[md][t][g] = seq(128xK) @ Wih0[md](Kx3072) + b
__global__ void __launch_bounds__(256) xw_gemm(const u16* Akp,
                                               const float* Wm0, const float* Wm1,
                                               const float* bm0, const float* bm1, float* out) {
  __shared__ u16 lds[48 * 64 * 8];
  int tid = threadIdx.x;
  int lane = tid & 63;
  int wave = tid >> 6;
  int md = blockIdx.y;
  int m = md >> 1;
  int dir = md & 1;
  const float* W = (m ? Wm1 : Wm0) + (size_t)dir * 3072 * 768;
  const float* b = (m ? bm1 : bm0) + dir * 3072;
  int g0 = blockIdx.x * 64;
  int quad = lane >> 4, l15 = lane & 15;
  v4f acc[2][4];
#pragma unroll
  for (int a = 0; a < 2; ++a)
#pragma unroll
    for (int nt = 0; nt < 4; ++nt) acc[a][nt] = (v4f){0.f, 0.f, 0.f, 0.f};

  for (int hfl = 0; hfl < 2; ++hfl) {
    if (hfl) __syncthreads();
    for (int it = 0; it < 12; ++it) {
      int ck = it * 256 + tid;
      int kb = ck >> 6;
      int r = ck & 63;
      const float* s = W + (size_t)(g0 + r) * 768 + (size_t)(hfl * 48 + kb) * 8;
      union { u16 h[8]; int4 v; } u;
#pragma unroll
      for (int j = 0; j < 8; ++j) u.h[j] = f2b(s[j]);
      *(int4*)(lds + (size_t)ck * 8) = u.v;
    }
    __syncthreads();
    for (int lt = 0; lt < 12; ++lt) {
      int kblk = (hfl * 12 + lt) * 4 + quad;
      v8s a0 = ((const v8s*)Akp)[(size_t)kblk * 128 + (wave * 2 + 0) * 16 + l15];
      v8s a1 = ((const v8s*)Akp)[(size_t)kblk * 128 + (wave * 2 + 1) * 16 + l15];
#pragma unroll
      for (int nt = 0; nt < 4; ++nt) {
        v8s bb = *(const v8s*)(lds + ((size_t)((lt * 4 + quad) * 64) + nt * 16 + l15) * 8);
        acc[0][nt] = MFMA(a0, bb, acc[0][nt]);
        acc[1][nt] = MFMA(a1, bb, acc[1][nt]);
      }
    }
  }
#pragma unroll
  for (int a = 0; a < 2; ++a)
#pragma unroll
    for (int nt = 0; nt < 4; ++nt) {
      int g = g0 + nt * 16 + l15;
      float bv = b[g];
#pragma unroll
      for (int r = 0; r < 4; ++r) {
        int trow = (wave * 2 + a) * 16 + quad * 4 + r;
        out[(size_t)(md * 128 + trow) * 3072 + g] = acc[a][nt][r] + bv;
      }
    }
}

// ---------------------------------------------------------------------------
// Persistent kernel: phase A (layer 0) -> grid bar -> xw1 GEMM -> phase B (layer 1)
__global__ void __launch_bounds__(256, 1) persist_k(
    const u16* __restrict__ W0kp, const u16* __restrict__ W1xkp,
    const u16* __restrict__ W1rkp, const float* __restrict__ xw0,
    const float* __restrict__ postWih1, const float* __restrict__ priWih1,
    const float* __restrict__ postb1, const float* __restrict__ prib1,
    u16* F0, u16* h0f, u16* B0, u16* F1, u16* B1, float* xw1s, unsigned* ctrs) {
  extern __shared__ u16 lds[];               // [0,96KB) resident, [96KB,144KB) stage
  u16* stg = lds + 49152;
  int tid = threadIdx.x;
  int lane = tid & 63;
  int wave = tid >> 6;
  int grp = blockIdx.x / 48;
  int jb = (blockIdx.x % 48) * 16;
  int quad = lane >> 4, l15 = lane & 15;
  int j = jb + l15;

  // ======================= Phase A: layer 0 =======================
  {
    int isf = grp >> 1;          // 0: bwd chains, 1: fwd chains
    int m = grp & 1;
    int dir = isf ? 0 : 1;
    const int4* wsrc = (const int4*)(W0kp + (size_t)(m * 2 + dir) * WMAT);
    int4* dres = (int4*)lds;
    for (int it = 0; it < 24; ++it) {
      int ck = it * 256 + tid;
      int kb = ck >> 6;
      int r = ck & 63;
      dres[ck] = wsrc[(size_t)kb * 3072 + (r >> 4) * 768 + jb + (r & 15)];
    }
    __syncthreads();

    float cr[4] = {0.f, 0.f, 0.f, 0.f};
    float hr[4] = {0.f, 0.f, 0.f, 0.f};
    unsigned* ctrA = ctrs + grp * 32;
    const float* xwbase = xw0 + (size_t)(m * 2 + dir) * 128 * 3072;

#pragma unroll 1
    for (int s = 0; s < 128; ++s) {
      int t = isf ? s : 127 - s;
      if (!isf) {
        const v8s* A = (const v8s*)(B0 + (size_t)(m * 129 + t + 1) * SLOT64);
        v4f acc[4];
#pragma unroll
        for (int gt = 0; gt < 4; ++gt) acc[gt] = (v4f){0.f, 0.f, 0.f, 0.f};
#pragma unroll 4
        for (int lt = 0; lt < 24; ++lt) {
          int kblk = lt * 4 + quad;
          v8s a = A[(size_t)kblk * 64 + wave * 16 + l15];
#pragma unroll
          for (int gt = 0; gt < 4; ++gt) {
            v8s bb = *(const v8s*)(lds + ((size_t)(kblk * 64 + gt * 16 + l15)) * 8);
            acc[gt] = MFMA(a, bb, acc[gt]);
          }
        }
        const float* xw = xwbase + (size_t)t * 3072;
        float xi = xw[j], xf = xw[768 + j], xg = xw[1536 + j], xo = xw[2304 + j];
        u16* dst = B0 + (size_t)(m * 129 + t) * SLOT64;
#pragma unroll
        for (int r = 0; r < 4; ++r) {
          int p = wave * 16 + quad * 4 + r;
          float gi = sigf(acc[0][r] + xi), gf = sigf(acc[1][r] + xf);
          float gg = tanhfast(acc[2][r] + xg), go = sigf(acc[3][r] + xo);
          float cn = gf * cr[r] + gi * gg;
          float hn = go * tanhfast(cn);
          bool act = t < (2 * p + 2 - m);
          cr[r] = act ? cn : cr[r];
          float he = act ? hn : hr[r];
          hr[r] = he;
          dst[((size_t)(j >> 3) * 64 + p) * 8 + (j & 7)] = f2b(he);
        }
      } else {
        if (wave == 0) {
          const v8s* A = (const v8s*)(F0 + (size_t)(m * 129 + t) * SLOT16);
          v4f acc[4];
#pragma unroll
          for (int gt = 0; gt < 4; ++gt) acc[gt] = (v4f){0.f, 0.f, 0.f, 0.f};
#pragma unroll 4
          for (int lt = 0; lt < 24; ++lt) {
            int kblk = lt * 4 + quad;
            v8s a = A[(size_t)kblk * 16 + l15];
#pragma unroll
            for (int gt = 0; gt < 4; ++gt) {
              v8s bb = *(const v8s*)(lds + ((size_t)(kblk * 64 + gt * 16 + l15)) * 8);
              acc[gt] = MFMA(a, bb, acc[gt]);
            }
          }
          if (quad == 0) {
            const float* xw = xwbase + (size_t)t * 3072;
            float gi = sigf(acc[0][0] + xw[j]), gf = sigf(acc[1][0] + xw[768 + j]);
            float gg = tanhfast(acc[2][0] + xw[1536 + j]), go = sigf(acc[3][0] + xw[2304 + j]);
            float cn = gf * cr[0] + gi * gg;
            float hn = go * tanhfast(cn);
            cr[0] = cn;
            F0[(size_t)(m * 129 + t + 1) * SLOT16 + ((size_t)(j >> 3) * 16) * 8 + (j & 7)] = f2b(hn);
            h0f[(size_t)m * SLOT128 + ((size_t)(j >> 3) * 128 + t) * 8 + (j & 7)] = f2b(hn);
          }
        }
      }
      gbar(ctrA, (unsigned)(s + 1) * 48);
    }
  }

  // full grid barrier: phase B mixes chains across groups
  gbar(ctrs + 8 * 32, 192);

  // ======================= xw1s: Wih1[:, :768] @ h0f + b1 =======================
  int md = grp;
  int m = md >> 1;
  int dir = md & 1;
  {
    const float* Wsrc = (m ? priWih1 : postWih1) + (size_t)dir * 3072 * 1536;
    for (int it = 0; it < 24; ++it) {
      int ck = it * 256 + tid;
      int kb = ck >> 6;
      int r = ck & 63;
      const float* sp = Wsrc + (size_t)((r >> 4) * 768 + jb + (r & 15)) * 1536 + (size_t)kb * 8;
      union { u16 h[8]; int4 v; } u;
#pragma unroll
      for (int q = 0; q < 8; ++q) u.h[q] = f2b(sp[q]);
      ((int4*)lds)[ck] = u.v;
    }
    __syncthreads();
    const v8s* A = (const v8s*)(h0f + (size_t)m * SLOT128);
    const float* bsl = (m ? prib1 : postb1) + dir * 3072;
    v4f acc2[2][4];
#pragma unroll
    for (int a = 0; a < 2; ++a)
#pragma unroll
      for (int gt = 0; gt < 4; ++gt) acc2[a][gt] = (v4f){0.f, 0.f, 0.f, 0.f};
    for (int lt = 0; lt < 24; ++lt) {
      int kblk = lt * 4 + quad;
      v8s a0 = A[(size_t)kblk * 128 + (wave * 2 + 0) * 16 + l15];
      v8s a1 = A[(size_t)kblk * 128 + (wave * 2 + 1) * 16 + l15];
#pragma unroll
      for (int gt = 0; gt < 4; ++gt) {
        v8s bb = *(const v8s*)(lds + ((size_t)(kblk * 64 + gt * 16 + l15)) * 8);
        acc2[0][gt] = MFMA(a0, bb, acc2[0][gt]);
        acc2[1][gt] = MFMA(a1, bb, acc2[1][gt]);
      }
    }
#pragma unroll
    for (int a = 0; a < 2; ++a)
#pragma unroll
      for (int gt = 0; gt < 4; ++gt) {
        int gG = gt * 768 + jb + l15;
        float bv = bsl[gG];
#pragma unroll
        for (int r = 0; r < 4; ++r) {
          int trow = (wave * 2 + a) * 16 + quad * 4 + r;
          xw1s[((size_t)md * 128 + trow) * 3072 + gG] = acc2[a][gt][r] + bv;
        }
      }
    __syncthreads();
  }

  // ======================= Phase B: layer 1 =======================
  {
    const int4* wr = (const int4*)(W1rkp + (size_t)md * WMAT);
    int4* dres = (int4*)lds;
    for (int it = 0; it < 24; ++it) {
      int ck = it * 256 + tid;
      int kb = ck >> 6;
      int r = ck & 63;
      dres[ck] = wr[(size_t)kb * 3072 + (r >> 4) * 768 + jb + (r & 15)];
    }
    __syncthreads();

    const int4* wx = (const int4*)(W1xkp + (size_t)md * WMAT);
    unsigned* ctrB = ctrs + (4 + md) * 32;
    float cr[4] = {0.f, 0.f, 0.f, 0.f};
    float hr[4] = {0.f, 0.f, 0.f, 0.f};

#pragma unroll 1
    for (int s = 0; s < 128; ++s) {
      int t = dir ? 127 - s : s;
      const v8s* A1 = (const v8s*)(B0 + (size_t)(m * 129 + t) * SLOT64);
      const v8s* A2 = (const v8s*)(dir ? (B1 + (size_t)(m * 129 + t + 1) * SLOT64)
                                       : (F1 + (size_t)(m * 129 + t) * SLOT64));
      v4f acc[4];
#pragma unroll
      for (int gt = 0; gt < 4; ++gt) acc[gt] = (v4f){0.f, 0.f, 0.f, 0.f};

      int4 rw[12];
#pragma unroll
      for (int it = 0; it < 12; ++it) {
        int ck = it * 256 + tid;
        int kb = ck >> 6;
        int r = ck & 63;
        rw[it] = wx[(size_t)kb * 3072 + (r >> 4) * 768 + jb + (r & 15)];
      }
      // recurrent part: W1r (LDS-resident) x A2 — overlaps the half0 loads
#pragma unroll 4
      for (int lt = 0; lt < 24; ++lt) {
        int kblk = lt * 4 + quad;
        v8s a = A2[(size_t)kblk * 64 + wave * 16 + l15];
#pragma unroll
        for (int gt = 0; gt < 4; ++gt) {
          v8s bb = *(const v8s*)(lds + ((size_t)(kblk * 64 + gt * 16 + l15)) * 8);
          acc[gt] = MFMA(a, bb, acc[gt]);
        }
      }
#pragma unroll
      for (int it = 0; it < 12; ++it) ((int4*)stg)[it * 256 + tid] = rw[it];
      __syncthreads();
      // prefetch half1 while consuming half0
#pragma unroll
      for (int it = 0; it < 12; ++it) {
        int ck = it * 256 + tid;
        int kb = 48 + (ck >> 6);
        int r = ck & 63;
        rw[it] = wx[(size_t)kb * 3072 + (r >> 4) * 768 + jb + (r & 15)];
      }
#pragma unroll 4
      for (int lt = 0; lt < 12; ++lt) {
        int kl = lt * 4 + quad;
        v8s a = A1[(size_t)kl * 64 + wave * 16 + l15];
#pragma unroll
        for (int gt = 0; gt < 4; ++gt) {
          v8s bb = *(const v8s*)(stg + ((size_t)(kl * 64 + gt * 16 + l15)) * 8);
          acc[gt] = MFMA(a, bb, acc[gt]);
        }
      }
      __syncthreads();
#pragma unroll
      for (int it = 0; it < 12; ++it) ((int4*)stg)[it * 256 + tid] = rw[it];
      __syncthreads();
#pragma unroll 4
      for (int lt = 0; lt < 12; ++lt) {
        int kl = lt * 4 + quad;
        v8s a = A1[(size_t)(48 + kl) * 64 + wave * 16 + l15];
#pragma unroll
        for (int gt = 0; gt < 4; ++gt) {
          v8s bb = *(const v8s*)(stg + ((size_t)(kl * 64 + gt * 16 + l15)) * 8);
          acc[gt] = MFMA(a, bb, acc[gt]);
        }
      }
      // epilogue
      const float* xw = xw1s + ((size_t)md * 128 + t) * 3072;
      float xi = xw[j], xf = xw[768 + j], xg = xw[1536 + j], xo = xw[2304 + j];
      u16* dst = dir ? (B1 + (size_t)(m * 129 + t) * SLOT64)
                     : (F1 + (size_t)(m * 129 + t + 1) * SLOT64);
#pragma unroll
      for (int r = 0; r < 4; ++r) {
        int p = wave * 16 + quad * 4 + r;
        float gi = sigf(acc[0][r] + xi), gf = sigf(acc[1][r] + xf);
        float gg = tanhfast(acc[2][r] + xg), go = sigf(acc[3][r] + xo);
        float cn = gf * cr[r] + gi * gg;
        float hn = go * tanhfast(cn);
        bool act = t < (2 * p + 2 - m);
        cr[r] = act ? cn : cr[r];
        float he = act ? hn : hr[r];
        hr[r] = he;
        dst[((size_t)(j >> 3) * 64 + p) * 8 + (j & 7)] = f2b(he);
      }
      gbar(ctrB, (unsigned)(s + 1) * 48);
    }
  }
}

__global__ void __launch_bounds__(256) em_k(const u16* F1, const u16* B1,
                                            const float* pW0, const float* pb0,
                                            const float* pW1, const float* pb1, float* em) {
  int wid = blockIdx.x * 4 + (threadIdx.x >> 6);
  int lane = threadIdx.x & 63;
  int m = wid >> 13;
  int rem = wid & 8191;
  int p = rem >> 7;
  int t = rem & 127;
  const u16* hf = F1 + (size_t)(m * 129 + t + 1) * SLOT64;
  const u16* hb = B1 + (size_t)(m * 129 + t) * SLOT64;
  const float* Pw = m ? pW1 : pW0;
  const float* Pb = m ? pb1 : pb0;
  float s0 = 0.f, s1 = 0.f;
#pragma unroll
  for (int i = 0; i < 12; ++i) {
    int j = i * 64 + lane;
    size_t o = ((size_t)(j >> 3) * 64 + p) * 8 + (j & 7);
    float vf = b2f(hf[o]);
    float vb = b2f(hb[o]);
    s0 += Pw[j] * vf + Pw[768 + j] * vb;
    s1 += Pw[1536 + j] * vf + Pw[2304 + j] * vb;
  }
  for (int off = 32; off; off >>= 1) {
    s0 += __shfl_down(s0, off, 64);
    s1 += __shfl_down(s1, off, 64);
  }
  if (lane == 0) {
    em[((size_t)(m * 64 + p) * 128 + t) * 2 + 0] = s0 + Pb[0];
    em[((size_t)(m * 64 + p) * 128 + t) * 2 + 1] = s1 + Pb[1];
  }
}

__global__ void final_k(const float* em, const int* labs, const float* T, float* out) {
  int p = threadIdx.x;
  const float* emP = em + (size_t)p * 128 * 2;
  int lp = 2 * p + 2;
  float T00 = T[0], T01 = T[1], T10 = T[2], T11 = T[3];
  int prevlab = labs[0];
  float gold = emP[prevlab];
  for (int t = 1; t < lp; ++t) {
    int lb = labs[t];
    gold += emP[t * 2 + lb] + (prevlab ? (lb ? T11 : T10) : (lb ? T01 : T00));
    prevlab = lb;
  }
  float a0 = emP[0], a1 = emP[1];
  for (int t = 1; t < lp; ++t) {
    float n0 = lse2(a0 + T00, a1 + T10) + emP[t * 2];
    float n1 = lse2(a0 + T01, a1 + T11) + emP[t * 2 + 1];
    a0 = n0;
    a1 = n1;
  }
  float crf = lse2(a0, a1) - gold;
  const float* emR = em + (size_t)(64 + p) * 128 * 2;
  int lpr = 2 * p + 1;
  float d0 = emR[(lpr - 1) * 2 + 0] - emP[(lp - 1) * 2 + 0];
  float d1 = emR[(lpr - 1) * 2 + 1] - emP[(lp - 1) * 2 + 1];
  float mse = d0 * d0 + d1 * d1;
  for (int off = 32; off; off >>= 1) {
    crf += __shfl_down(crf, off, 64);
    mse += __shfl_down(mse, off, 64);
  }
  if (p == 0) {
    float lc = crf / 64.f;
    float lm = mse / 128.f;
    out[0] = lc;
    out[1] = lm;
    out[2] = lc + 0.1f * lm;
  }
}

// ---------------------------------------------------------------------------
extern "C" void kernel_launch(void* const* d_in, const int* in_sizes, int n_in,
                              void* d_out, int out_size, void* d_ws, size_t ws_size,
                              hipStream_t stream) {
  (void)in_sizes; (void)n_in; (void)out_size;
  if (ws_size < WS_NEED) return;

  const float* user     = (const float*)d_in[0];
  const float* sysr     = (const float*)d_in[1];
  const float* postWih0 = (const float*)d_in[2];
  const float* postWhh0 = (const float*)d_in[3];
  const float* postb0   = (const float*)d_in[4];
  const float* postWih1 = (const float*)d_in[5];
  const float* postWhh1 = (const float*)d_in[6];
  const float* postb1   = (const float*)d_in[7];
  const float* priWih0  = (const float*)d_in[8];
  const float* priWhh0  = (const float*)d_in[9];
  const float* prib0    = (const float*)d_in[10];
  const float* priWih1  = (const float*)d_in[11];
  const float* priWhh1  = (const float*)d_in[12];
  const float* prib1    = (const float*)d_in[13];
  const float* postPW   = (const float*)d_in[14];
  const float* postPb   = (const float*)d_in[15];
  const float* priPW    = (const float*)d_in[16];
  const float* priPb    = (const float*)d_in[17];
  const float* trans    = (const float*)d_in[18];
  const int*   ulab     = (const int*)d_in[19];
  const int*   slab     = (const int*)d_in[20];
  float* out = (float*)d_out;

  char* w = (char*)d_ws;
  unsigned* ctrs = (unsigned*)(w + OFF_CTR);
  float* em    = (float*)(w + OFF_EM);
  float* xw0   = (float*)(w + OFF_XW0);
  float* xw1s  = (float*)(w + OFF_XW1);
  u16* seqkp   = (u16*)(w + OFF_SEQ);
  int* labs    = (int*)(w + OFF_LABS);
  u16* W0kp    = (u16*)(w + OFF_W0);
  u16* W1xkp   = (u16*)(w + OFF_W1X);
  u16* W1rkp   = (u16*)(w + OFF_W1R);
  u16* F0      = (u16*)(w + OFF_F0);
  u16* h0f     = (u16*)(w + OFF_H0F);
  u16* B0      = (u16*)(w + OFF_B0);
  u16* F1      = (u16*)(w + OFF_F1);
  u16* B1      = (u16*)(w + OFF_B1);

  init_zero<<<192, 256, 0, stream>>>(
      F0, F0 + (size_t)129 * SLOT16,
      B0 + (size_t)128 * SLOT64, B0 + (size_t)(129 + 128) * SLOT64,
      F1, F1 + (size_t)129 * SLOT64,
      B1 + (size_t)128 * SLOT64, B1 + (size_t)(129 + 128) * SLOT64, ctrs);

  build_seq<<<384, 256, 0, stream>>>(user, sysr, ulab, slab, seqkp, labs);

  cvt_w<<<dim3(1152, 12), 256, 0, stream>>>(postWhh0, priWhh0, postWih1, priWih1,
                                            postWhh1, priWhh1, W0kp, W1xkp, W1rkp);

  xw_gemm<<<dim3(48, 4), 256, 0, stream>>>(seqkp, postWih0, priWih0, postb0, prib0, xw0);

  {
    const u16* a0 = W0kp; const u16* a1 = W1xkp; const u16* a2 = W1rkp;
    const float* a3 = xw0;
    void* args[] = {(void*)&a0, (void*)&a1, (void*)&a2, (void*)&a3,
                    (void*)&postWih1, (void*)&priWih1, (void*)&postb1, (void*)&prib1,
                    (void*)&F0, (void*)&h0f, (void*)&B0, (void*)&F1, (void*)&B1,
                    (void*)&xw1s, (void*)&ctrs};
    hipError_t e = hipLaunchCooperativeKernel((const void*)persist_k, dim3(192), dim3(256),
                                              args, LDS_BYTES, stream);
    if (e != hipSuccess) {
      // fallback: plain launch (192 blocks @ 1/CU co-reside on 256 CUs)
      persist_k<<<192, 256, LDS_BYTES, stream>>>(W0kp, W1xkp, W1rkp, xw0, postWih1, priWih1,
                                                 postb1, prib1, F0, h0f, B0, F1, B1, xw1s, ctrs);
    }
  }

  em_k<<<4096, 256, 0, stream>>>(F1, B1, postPW, postPb, priPW, priPb, em);

  final_k<<<1, 64, 0, stream>>>(em, labs, trans, out);
}

// Round 3
// 5474.805 us; speedup vs baseline: 1.0991x; 1.0991x over previous
//
#include <hip/hip_runtime.h>

// ---------------------------------------------------------------------------
// VanillaCRF forward on MI355X — R3: persistent A/B kernels with relaxed
// (cache-maintenance-free) barriers; cross-XCD h-state via sc1 atomics.
// kp layout: elem(row r, col k) at base[((k>>3)*R + r)*8 + (k&7)].
// Frags (m89/m91): A[m=lane&15][k=quad*8+j], B[k=quad*8+j][n=lane&15],
// D[row=quad*4+reg][col=lane&15].
// ---------------------------------------------------------------------------

typedef short v8s __attribute__((ext_vector_type(8)));
typedef float v4f __attribute__((ext_vector_type(4)));
typedef unsigned short u16;
typedef unsigned long long u64;

#define MFMA(a, b, c) __builtin_amdgcn_mfma_f32_16x16x32_bf16((a), (b), (c), 0, 0, 0)

static constexpr size_t WMAT    = (size_t)96 * 3072 * 8;
static constexpr size_t SLOT64  = (size_t)96 * 64 * 8;
static constexpr size_t SLOT16  = (size_t)96 * 16 * 8;
static constexpr size_t SLOT128 = (size_t)96 * 128 * 8;

static constexpr size_t OFF_CTR  = 0;
static constexpr size_t SZ_CTR   = 4096;
static constexpr size_t OFF_EM   = OFF_CTR + SZ_CTR;
static constexpr size_t SZ_EM    = (size_t)2 * 64 * 128 * 2 * 4;
static constexpr size_t OFF_XW0  = OFF_EM + SZ_EM;
static constexpr size_t SZ_XW    = (size_t)4 * 128 * 3072 * 4;
static constexpr size_t OFF_XW1  = OFF_XW0 + SZ_XW;
static constexpr size_t OFF_SEQ  = OFF_XW1 + SZ_XW;
static constexpr size_t SZ_SEQ   = (size_t)96 * 128 * 8 * 2;
static constexpr size_t OFF_LABS = OFF_SEQ + SZ_SEQ;
static constexpr size_t SZ_LABS  = 512;
static constexpr size_t OFF_W0   = OFF_LABS + SZ_LABS;
static constexpr size_t SZ_W4    = (size_t)4 * WMAT * 2;
static constexpr size_t OFF_W1X  = OFF_W0 + SZ_W4;
static constexpr size_t OFF_W1R  = OFF_W1X + SZ_W4;
static constexpr size_t OFF_F0   = OFF_W1R + SZ_W4;
static constexpr size_t SZ_F0    = (size_t)2 * 129 * SLOT16 * 2;
static constexpr size_t OFF_H0F  = OFF_F0 + SZ_F0;
static constexpr size_t SZ_H0F   = (size_t)2 * SLOT128 * 2;
static constexpr size_t OFF_B0   = OFF_H0F + SZ_H0F;
static constexpr size_t SZ_S64   = (size_t)2 * 129 * SLOT64 * 2;
static constexpr size_t OFF_F1   = OFF_B0 + SZ_S64;
static constexpr size_t OFF_B1   = OFF_F1 + SZ_S64;
static constexpr size_t WS_NEED  = OFF_B1 + SZ_S64;   // ~145 MB

static constexpr unsigned LDSA_BYTES = 98304;    // 96 KB resident
static constexpr unsigned LDSB_BYTES = 147456;   // 96 KB resident + 48 KB stage

static __device__ __forceinline__ u16 f2b(float f) {
  unsigned int u = __float_as_uint(f);
  unsigned int r = (u + 0x7FFFu + ((u >> 16) & 1u)) >> 16;
  return (u16)r;
}
static __device__ __forceinline__ float b2f(u16 u) {
  return __uint_as_float(((unsigned int)u) << 16);
}
static __device__ __forceinline__ float sigf(float x) { return 1.0f / (1.0f + __expf(-x)); }
static __device__ __forceinline__ float tanhfast(float x) {
  return 1.0f - 2.0f / (__expf(2.0f * x) + 1.0f);
}
static __device__ __forceinline__ float lse2(float a, float b) {
  float mx = fmaxf(a, b);
  return mx + __logf(__expf(a - mx) + __expf(b - mx));
}

// device-visible (sc1, L2-bypass) 16-byte fragment load, relaxed
static __device__ __forceinline__ v8s aload16(const u16* p) {
  union { u64 q[2]; v8s v; } u;
  u.q[0] = __hip_atomic_load((u64*)p,     __ATOMIC_RELAXED, __HIP_MEMORY_SCOPE_AGENT);
  u.q[1] = __hip_atomic_load((u64*)p + 1, __ATOMIC_RELAXED, __HIP_MEMORY_SCOPE_AGENT);
  return u.v;
}
// device-visible packed u32 store
static __device__ __forceinline__ void astore32(u16* p, unsigned v) {
  __hip_atomic_store((unsigned*)p, v, __ATOMIC_RELAXED, __HIP_MEMORY_SCOPE_AGENT);
}
static __device__ __forceinline__ unsigned aload32(const u16* p) {
  return __hip_atomic_load((unsigned*)p, __ATOMIC_RELAXED, __HIP_MEMORY_SCOPE_AGENT);
}

// relaxed group barrier: no cache maintenance. __syncthreads drains vmcnt
// (compiler emits full s_waitcnt before s_barrier), so this block's sc1
// stores are device-visible before arrive.
static __device__ __forceinline__ void gbar_relaxed(unsigned* ctr, unsigned target) {
  __syncthreads();
  if (threadIdx.x == 0) {
    __hip_atomic_fetch_add(ctr, 1u, __ATOMIC_RELAXED, __HIP_MEMORY_SCOPE_AGENT);
    while (__hip_atomic_load(ctr, __ATOMIC_RELAXED, __HIP_MEMORY_SCOPE_AGENT) < target)
      __builtin_amdgcn_s_sleep(2);
  }
  __syncthreads();
}

// ---------------------------------------------------------------------------
__global__ void init_zero(u16* f0a, u16* f0b, u16* b0a, u16* b0b,
                          u16* f1a, u16* f1b, u16* b1a, u16* b1b, unsigned* ctrs) {
  int idx = blockIdx.x * 256 + threadIdx.x;   // grid 192 -> 49152 == SLOT64
  if (idx < 1024) ctrs[idx] = 0;
  if (idx < (int)SLOT16) { f0a[idx] = 0; f0b[idx] = 0; }
  b0a[idx] = 0; b0b[idx] = 0;
  f1a[idx] = 0; f1b[idx] = 0;
  b1a[idx] = 0; b1b[idx] = 0;
}

__global__ void build_seq(const float* user, const float* sysr, const int* ulab,
                          const int* slab, u16* seqkp, int* labs) {
  int idx = blockIdx.x * 256 + threadIdx.x;   // grid 384
  int t = idx / 768;
  int hh = idx - t * 768;
  float v = (t & 1) ? sysr[(t >> 1) * 768 + hh] : user[(t >> 1) * 768 + hh];
  seqkp[((size_t)(hh >> 3) * 128 + t) * 8 + (hh & 7)] = f2b(v);
  if (idx < 128) labs[idx] = (idx & 1) ? slab[idx >> 1] : ulab[idx >> 1];
}

// 12 matrices -> kp bf16: grp0 Whh0, grp1 Wih1[:,768:], grp2 Whh1
__global__ void cvt_w(const float* postWhh0, const float* priWhh0,
                      const float* postWih1, const float* priWih1,
                      const float* postWhh1, const float* priWhh1,
                      u16* W0kp, u16* W1xkp, u16* W1rkp) {
  int mat = blockIdx.y;
  int grp = mat >> 2;
  int sub = mat & 3;
  int m = sub >> 1;
  int dirw = sub & 1;
  const float* src;
  int stride, coff;
  u16* dstb;
  if (grp == 0)      { src = m ? priWhh0 : postWhh0; stride = 768;  coff = 0;   dstb = W0kp; }
  else if (grp == 1) { src = m ? priWih1 : postWih1; stride = 1536; coff = 768; dstb = W1xkp; }
  else               { src = m ? priWhh1 : postWhh1; stride = 768;  coff = 0;   dstb = W1rkp; }
  src += (size_t)dirw * 3072 * stride;
  int cid = blockIdx.x * 256 + threadIdx.x;   // grid.x = 1152
  int g = cid / 96;
  int kb = cid - g * 96;
  const float* s = src + (size_t)g * stride + coff + (size_t)kb * 8;
  union { u16 h[8]; int4 v; } u;
#pragma unroll
  for (int j = 0; j < 8; ++j) u.h[j] = f2b(s[j]);
  ((int4*)(dstb + (size_t)sub * WMAT))[(size_t)kb * 3072 + g] = u.v;
}

// out[md][t][g] = seq(128xK) @ Wih0[md](Kx3072) + b
__global__ void __launch_bounds__(256) xw_gemm(const u16* Akp,
                                               const float* Wm0, const float* Wm1,
                                               const float* bm0, const float* bm1, float* out) {
  __shared__ u16 lds[48 * 64 * 8];
  int tid = threadIdx.x;
  int lane = tid & 63;
  int wave = tid >> 6;
  int md = blockIdx.y;
  int m = md >> 1;
  int dir = md & 1;
  const float* W = (m ? Wm1 : Wm0) + (size_t)dir * 3072 * 768;
  const float* b = (m ? bm1 : bm0) + dir * 3072;
  int g0 = blockIdx.x * 64;
  int quad = lane >> 4, l15 = lane & 15;
  v4f acc[2][4];
#pragma unroll
  for (int a = 0; a < 2; ++a)
#pragma unroll
    for (int nt = 0; nt < 4; ++nt) acc[a][nt] = (v4f){0.f, 0.f, 0.f, 0.f};

  for (int hfl = 0; hfl < 2; ++hfl) {
    if (hfl) __syncthreads();
    for (int it = 0; it < 12; ++it) {
      int ck = it * 256 + tid;
      int kb = ck >> 6;
      int r = ck & 63;
      const float* s = W + (size_t)(g0 + r) * 768 + (size_t)(hfl * 48 + kb) * 8;
      union { u16 h[8]; int4 v; } u;
#pragma unroll
      for (int j = 0; j < 8; ++j) u.h[j] = f2b(s[j]);
      *(int4*)(lds + (size_t)ck * 8) = u.v;
    }
    __syncthreads();
    for (int lt = 0; lt < 12; ++lt) {
      int kblk = (hfl * 12 + lt) * 4 + quad;
      v8s a0 = ((const v8s*)Akp)[(size_t)kblk * 128 + (wave * 2 + 0) * 16 + l15];
      v8s a1 = ((const v8s*)Akp)[(size_t)kblk * 128 + (wave * 2 + 1) * 16 + l15];
#pragma unroll
      for (int nt = 0; nt < 4; ++nt) {
        v8s bb = *(const v8s*)(lds + ((size_t)((lt * 4 + quad) * 64) + nt * 16 + l15) * 8);
        acc[0][nt] = MFMA(a0, bb, acc[0][nt]);
        acc[1][nt] = MFMA(a1, bb, acc[1][nt]);
      }
    }
  }
#pragma unroll
  for (int a = 0; a < 2; ++a)
#pragma unroll
    for (int nt = 0; nt < 4; ++nt) {
      int g = g0 + nt * 16 + l15;
      float bv = b[g];
#pragma unroll
      for (int r = 0; r < 4; ++r) {
        int trow = (wave * 2 + a) * 16 + quad * 4 + r;
        out[(size_t)(md * 128 + trow) * 3072 + g] = acc[a][nt][r] + bv;
      }
    }
}

// ---------------------------------------------------------------------------
// Persistent phase A: layer-0 chains. grp 0/1 = bwd post/prior (full batch),
// grp 2/3 = fwd post/prior (batch-degenerate, wave0 only).
__global__ void __launch_bounds__(256, 1) persistA_k(
    const u16* __restrict__ W0kp, const float* __restrict__ xw0,
    u16* F0, u16* h0f, u16* B0, unsigned* ctrs) {
  extern __shared__ u16 lds[];   // 96 KB: Whh0 slice resident
  int tid = threadIdx.x;
  int lane = tid & 63;
  int wave = tid >> 6;
  int grp = blockIdx.x / 48;
  int jb = (blockIdx.x % 48) * 16;
  int quad = lane >> 4, l15 = lane & 15;
  int j = jb + l15;
  int isf = grp >> 1;
  int m = grp & 1;
  int dir = isf ? 0 : 1;

  const int4* wsrc = (const int4*)(W0kp + (size_t)(m * 2 + dir) * WMAT);
  int4* dres = (int4*)lds;
  for (int it = 0; it < 24; ++it) {
    int ck = it * 256 + tid;
    int kb = ck >> 6;
    int r = ck & 63;
    dres[ck] = wsrc[(size_t)kb * 3072 + (r >> 4) * 768 + jb + (r & 15)];
  }
  __syncthreads();

  float cr[4] = {0.f, 0.f, 0.f, 0.f};
  float hr[4] = {0.f, 0.f, 0.f, 0.f};
  unsigned* ctrA = ctrs + grp * 32;
  const float* xwbase = xw0 + (size_t)(m * 2 + dir) * 128 * 3072;

#pragma unroll 1
  for (int s = 0; s < 128; ++s) {
    int t = isf ? s : 127 - s;
    if (!isf) {
      const u16* A = B0 + (size_t)(m * 129 + t + 1) * SLOT64;
      v4f acc[4];
#pragma unroll
      for (int gt = 0; gt < 4; ++gt) acc[gt] = (v4f){0.f, 0.f, 0.f, 0.f};
#pragma unroll 4
      for (int lt = 0; lt < 24; ++lt) {
        int kblk = lt * 4 + quad;
        v8s a = aload16(A + (size_t)(kblk * 64 + wave * 16 + l15) * 8);
#pragma unroll
        for (int gt = 0; gt < 4; ++gt) {
          v8s bb = *(const v8s*)(lds + ((size_t)(kblk * 64 + gt * 16 + l15)) * 8);
          acc[gt] = MFMA(a, bb, acc[gt]);
        }
      }
      const float* xw = xwbase + (size_t)t * 3072;
      float xi = xw[j], xf = xw[768 + j], xg = xw[1536 + j], xo = xw[2304 + j];
      u16* dst = B0 + (size_t)(m * 129 + t) * SLOT64;
#pragma unroll
      for (int r = 0; r < 4; ++r) {
        int p = wave * 16 + quad * 4 + r;
        float gi = sigf(acc[0][r] + xi), gf = sigf(acc[1][r] + xf);
        float gg = tanhfast(acc[2][r] + xg), go = sigf(acc[3][r] + xo);
        float cn = gf * cr[r] + gi * gg;
        float hn = go * tanhfast(cn);
        bool act = t < (2 * p + 2 - m);
        cr[r] = act ? cn : cr[r];
        float he = act ? hn : hr[r];
        hr[r] = he;
        int mine = (int)f2b(he);
        int part = __shfl_xor(mine, 1, 64);
        if (!(l15 & 1))
          astore32(dst + ((size_t)(j >> 3) * 64 + p) * 8 + (j & 7),
                   (unsigned)(mine & 0xffff) | ((unsigned)part << 16));
      }
    } else if (wave == 0) {
      const u16* A = F0 + (size_t)(m * 129 + t) * SLOT16;
      v4f acc[4];
#pragma unroll
      for (int gt = 0; gt < 4; ++gt) acc[gt] = (v4f){0.f, 0.f, 0.f, 0.f};
#pragma unroll 4
      for (int lt = 0; lt < 24; ++lt) {
        int kblk = lt * 4 + quad;
        v8s a = aload16(A + (size_t)(kblk * 16 + l15) * 8);
#pragma unroll
        for (int gt = 0; gt < 4; ++gt) {
          v8s bb = *(const v8s*)(lds + ((size_t)(kblk * 64 + gt * 16 + l15)) * 8);
          acc[gt] = MFMA(a, bb, acc[gt]);
        }
      }
      if (quad == 0) {
        const float* xw = xwbase + (size_t)t * 3072;
        float gi = sigf(acc[0][0] + xw[j]), gf = sigf(acc[1][0] + xw[768 + j]);
        float gg = tanhfast(acc[2][0] + xw[1536 + j]), go = sigf(acc[3][0] + xw[2304 + j]);
        float cn = gf * cr[0] + gi * gg;
        float hn = go * tanhfast(cn);
        cr[0] = cn;
        int mine = (int)f2b(hn);
        int part = __shfl_xor(mine, 1, 64);
        if (!(l15 & 1))
          astore32(F0 + (size_t)(m * 129 + t + 1) * SLOT16 + ((size_t)(j >> 3) * 16) * 8 + (j & 7),
                   (unsigned)(mine & 0xffff) | ((unsigned)part << 16));
        // h0f consumed only after kernel boundary -> normal store
        h0f[(size_t)m * SLOT128 + ((size_t)(j >> 3) * 128 + t) * 8 + (j & 7)] = f2b(hn);
      }
    }
    gbar_relaxed(ctrA, (unsigned)(s + 1) * 48);
  }
}

// ---------------------------------------------------------------------------
// Persistent phase B: xw1s block-local GEMM, then layer-1 chains.
__global__ void __launch_bounds__(256, 1) persistB_k(
    const u16* __restrict__ W1xkp, const u16* __restrict__ W1rkp,
    const float* __restrict__ postWih1, const float* __restrict__ priWih1,
    const float* __restrict__ postb1, const float* __restrict__ prib1,
    const u16* __restrict__ h0f, const u16* __restrict__ B0,
    u16* F1, u16* B1, float* xw1s, unsigned* ctrs) {
  extern __shared__ u16 lds[];               // [0,96KB) resident, [96KB,144KB) stage
  u16* stg = lds + 49152;
  int tid = threadIdx.x;
  int lane = tid & 63;
  int wave = tid >> 6;
  int md = blockIdx.x / 48;
  int jb = (blockIdx.x % 48) * 16;
  int quad = lane >> 4, l15 = lane & 15;
  int j = jb + l15;
  int m = md >> 1;
  int dir = md & 1;

  // ---- xw1s[md][t][g] for g in this block's 4x16 gate strip (producer==consumer) ----
  {
    const float* Wsrc = (m ? priWih1 : postWih1) + (size_t)dir * 3072 * 1536;
    for (int it = 0; it < 24; ++it) {
      int ck = it * 256 + tid;
      int kb = ck >> 6;
      int r = ck & 63;
      const float* sp = Wsrc + (size_t)((r >> 4) * 768 + jb + (r & 15)) * 1536 + (size_t)kb * 8;
      union { u16 h[8]; int4 v; } u;
#pragma unroll
      for (int q = 0; q < 8; ++q) u.h[q] = f2b(sp[q]);
      ((int4*)lds)[ck] = u.v;
    }
    __syncthreads();
    const v8s* A = (const v8s*)(h0f + (size_t)m * SLOT128);
    const float* bsl = (m ? prib1 : postb1) + dir * 3072;
    v4f acc2[2][4];
#pragma unroll
    for (int a = 0; a < 2; ++a)
#pragma unroll
      for (int gt = 0; gt < 4; ++gt) acc2[a][gt] = (v4f){0.f, 0.f, 0.f, 0.f};
    for (int lt = 0; lt < 24; ++lt) {
      int kblk = lt * 4 + quad;
      v8s a0 = A[(size_t)kblk * 128 + (wave * 2 + 0) * 16 + l15];
      v8s a1 = A[(size_t)kblk * 128 + (wave * 2 + 1) * 16 + l15];
#pragma unroll
      for (int gt = 0; gt < 4; ++gt) {
        v8s bb = *(const v8s*)(lds + ((size_t)(kblk * 64 + gt * 16 + l15)) * 8);
        acc2[0][gt] = MFMA(a0, bb, acc2[0][gt]);
        acc2[1][gt] = MFMA(a1, bb, acc2[1][gt]);
      }
    }
#pragma unroll
    for (int a = 0; a < 2; ++a)
#pragma unroll
      for (int gt = 0; gt < 4; ++gt) {
        int gG = gt * 768 + jb + l15;
        float bv = bsl[gG];
#pragma unroll
        for (int r = 0; r < 4; ++r) {
          int trow = (wave * 2 + a) * 16 + quad * 4 + r;
          xw1s[((size_t)md * 128 + trow) * 3072 + gG] = acc2[a][gt][r] + bv;
        }
      }
    __syncthreads();
  }

  // ---- layer-1 chain ----
  {
    const int4* wr = (const int4*)(W1rkp + (size_t)md * WMAT);
    int4* dres = (int4*)lds;
    for (int it = 0; it < 24; ++it) {
      int ck = it * 256 + tid;
      int kb = ck >> 6;
      int r = ck & 63;
      dres[ck] = wr[(size_t)kb * 3072 + (r >> 4) * 768 + jb + (r & 15)];
    }
    __syncthreads();

    const int4* wx = (const int4*)(W1xkp + (size_t)md * WMAT);
    unsigned* ctrB = ctrs + (4 + md) * 32;
    float cr[4] = {0.f, 0.f, 0.f, 0.f};
    float hr[4] = {0.f, 0.f, 0.f, 0.f};

#pragma unroll 1
    for (int s = 0; s < 128; ++s) {
      int t = dir ? 127 - s : s;
      const v8s* A1 = (const v8s*)(B0 + (size_t)(m * 129 + t) * SLOT64);   // static, cached
      const u16* A2 = dir ? (B1 + (size_t)(m * 129 + t + 1) * SLOT64)
                          : (F1 + (size_t)(m * 129 + t) * SLOT64);         // fresh, sc1
      v4f acc[4];
#pragma unroll
      for (int gt = 0; gt < 4; ++gt) acc[gt] = (v4f){0.f, 0.f, 0.f, 0.f};

      int4 rw[12];
#pragma unroll
      for (int it = 0; it < 12; ++it) {
        int ck = it * 256 + tid;
        int kb = ck >> 6;
        int r = ck & 63;
        rw[it] = wx[(size_t)kb * 3072 + (r >> 4) * 768 + jb + (r & 15)];
      }
      // recurrent part: W1r (LDS-resident) x A2 — overlaps the wx half0 loads
#pragma unroll 4
      for (int lt = 0; lt < 24; ++lt) {
        int kblk = lt * 4 + quad;
        v8s a = aload16(A2 + (size_t)(kblk * 64 + wave * 16 + l15) * 8);
#pragma unroll
        for (int gt = 0; gt < 4; ++gt) {
          v8s bb = *(const v8s*)(lds + ((size_t)(kblk * 64 + gt * 16 + l15)) * 8);
          acc[gt] = MFMA(a, bb, acc[gt]);
        }
      }
#pragma unroll
      for (int it = 0; it < 12; ++it) ((int4*)stg)[it * 256 + tid] = rw[it];
      __syncthreads();
#pragma unroll
      for (int it = 0; it < 12; ++it) {
        int ck = it * 256 + tid;
        int kb = 48 + (ck >> 6);
        int r = ck & 63;
        rw[it] = wx[(size_t)kb * 3072 + (r >> 4) * 768 + jb + (r & 15)];
      }
#pragma unroll 4
      for (int lt = 0; lt < 12; ++lt) {
        int kl = lt * 4 + quad;
        v8s a = A1[(size_t)kl * 64 + wave * 16 + l15];
#pragma unroll
        for (int gt = 0; gt < 4; ++gt) {
          v8s bb = *(const v8s*)(stg + ((size_t)(kl * 64 + gt * 16 + l15)) * 8);
          acc[gt] = MFMA(a, bb, acc[gt]);
        }
      }
      __syncthreads();
#pragma unroll
      for (int it = 0; it < 12; ++it) ((int4*)stg)[it * 256 + tid] = rw[it];
      __syncthreads();
#pragma unroll 4
      for (int lt = 0; lt < 12; ++lt) {
        int kl = lt * 4 + quad;
        v8s a = A1[(size_t)(48 + kl) * 64 + wave * 16 + l15];
#pragma unroll
        for (int gt = 0; gt < 4; ++gt) {
          v8s bb = *(const v8s*)(stg + ((size_t)(kl * 64 + gt * 16 + l15)) * 8);
          acc[gt] = MFMA(a, bb, acc[gt]);
        }
      }
      // epilogue
      const float* xw = xw1s + ((size_t)md * 128 + t) * 3072;
      float xi = xw[j], xf = xw[768 + j], xg = xw[1536 + j], xo = xw[2304 + j];
      u16* dst = dir ? (B1 + (size_t)(m * 129 + t) * SLOT64)
                     : (F1 + (size_t)(m * 129 + t + 1) * SLOT64);
#pragma unroll
      for (int r = 0; r < 4; ++r) {
        int p = wave * 16 + quad * 4 + r;
        float gi = sigf(acc[0][r] + xi), gf = sigf(acc[1][r] + xf);
        float gg = tanhfast(acc[2][r] + xg), go = sigf(acc[3][r] + xo);
        float cn = gf * cr[r] + gi * gg;
        float hn = go * tanhfast(cn);
        bool act = t < (2 * p + 2 - m);
        cr[r] = act ? cn : cr[r];
        float he = act ? hn : hr[r];
        hr[r] = he;
        int mine = (int)f2b(he);
        int part = __shfl_xor(mine, 1, 64);
        if (!(l15 & 1))
          astore32(dst + ((size_t)(j >> 3) * 64 + p) * 8 + (j & 7),
                   (unsigned)(mine & 0xffff) | ((unsigned)part << 16));
      }
      gbar_relaxed(ctrB, (unsigned)(s + 1) * 48);
    }
  }
}

__global__ void __launch_bounds__(256) em_k(const u16* F1, const u16* B1,
                                            const float* pW0, const float* pb0,
                                            const float* pW1, const float* pb1, float* em) {
  int wid = blockIdx.x * 4 + (threadIdx.x >> 6);
  int lane = threadIdx.x & 63;
  int m = wid >> 13;
  int rem = wid & 8191;
  int p = rem >> 7;
  int t = rem & 127;
  const u16* hf = F1 + (size_t)(m * 129 + t + 1) * SLOT64;
  const u16* hb = B1 + (size_t)(m * 129 + t) * SLOT64;
  const float* Pw = m ? pW1 : pW0;
  const float* Pb = m ? pb1 : pb0;
  float s0 = 0.f, s1 = 0.f;
#pragma unroll
  for (int i = 0; i < 12; ++i) {
    int j = i * 64 + lane;
    size_t o = ((size_t)(j >> 3) * 64 + p) * 8 + (j & 7);
    float vf = b2f(hf[o]);
    float vb = b2f(hb[o]);
    s0 += Pw[j] * vf + Pw[768 + j] * vb;
    s1 += Pw[1536 + j] * vf + Pw[2304 + j] * vb;
  }
  for (int off = 32; off; off >>= 1) {
    s0 += __shfl_down(s0, off, 64);
    s1 += __shfl_down(s1, off, 64);
  }
  if (lane == 0) {
    em[((size_t)(m * 64 + p) * 128 + t) * 2 + 0] = s0 + Pb[0];
    em[((size_t)(m * 64 + p) * 128 + t) * 2 + 1] = s1 + Pb[1];
  }
}

__global__ void final_k(const float* em, const int* labs, const float* T, float* out) {
  int p = threadIdx.x;
  const float* emP = em + (size_t)p * 128 * 2;
  int lp = 2 * p + 2;
  float T00 = T[0], T01 = T[1], T10 = T[2], T11 = T[3];
  int prevlab = labs[0];
  float gold = emP[prevlab];
  for (int t = 1; t < lp; ++t) {
    int lb = labs[t];
    gold += emP[t * 2 + lb] + (prevlab ? (lb ? T11 : T10) : (lb ? T01 : T00));
    prevlab = lb;
  }
  float a0 = emP[0], a1 = emP[1];
  for (int t = 1; t < lp; ++t) {
    float n0 = lse2(a0 + T00, a1 + T10) + emP[t * 2];
    float n1 = lse2(a0 + T01, a1 + T11) + emP[t * 2 + 1];
    a0 = n0;
    a1 = n1;
  }
  float crf = lse2(a0, a1) - gold;
  const float* emR = em + (size_t)(64 + p) * 128 * 2;
  int lpr = 2 * p + 1;
  float d0 = emR[(lpr - 1) * 2 + 0] - emP[(lp - 1) * 2 + 0];
  float d1 = emR[(lpr - 1) * 2 + 1] - emP[(lp - 1) * 2 + 1];
  float mse = d0 * d0 + d1 * d1;
  for (int off = 32; off; off >>= 1) {
    crf += __shfl_down(crf, off, 64);
    mse += __shfl_down(mse, off, 64);
  }
  if (p == 0) {
    float lc = crf / 64.f;
    float lm = mse / 128.f;
    out[0] = lc;
    out[1] = lm;
    out[2] = lc + 0.1f * lm;
  }
}

// ---------------------------------------------------------------------------
extern "C" void kernel_launch(void* const* d_in, const int* in_sizes, int n_in,
                              void* d_out, int out_size, void* d_ws, size_t ws_size,
                              hipStream_t stream) {
  (void)in_sizes; (void)n_in; (void)out_size;
  if (ws_size < WS_NEED) return;

  const float* user     = (const float*)d_in[0];
  const float* sysr     = (const float*)d_in[1];
  const float* postWih0 = (const float*)d_in[2];
  const float* postWhh0 = (const float*)d_in[3];
  const float* postb0   = (const float*)d_in[4];
  const float* postWih1 = (const float*)d_in[5];
  const float* postWhh1 = (const float*)d_in[6];
  const float* postb1   = (const float*)d_in[7];
  const float* priWih0  = (const float*)d_in[8];
  const float* priWhh0  = (const float*)d_in[9];
  const float* prib0    = (const float*)d_in[10];
  const float* priWih1  = (const float*)d_in[11];
  const float* priWhh1  = (const float*)d_in[12];
  const float* prib1    = (const float*)d_in[13];
  const float* postPW   = (const float*)d_in[14];
  const float* postPb   = (const float*)d_in[15];
  const float* priPW    = (const float*)d_in[16];
  const float* priPb    = (const float*)d_in[17];
  const float* trans    = (const float*)d_in[18];
  const int*   ulab     = (const int*)d_in[19];
  const int*   slab     = (const int*)d_in[20];
  float* out = (float*)d_out;

  char* w = (char*)d_ws;
  unsigned* ctrs = (unsigned*)(w + OFF_CTR);
  float* em    = (float*)(w + OFF_EM);
  float* xw0   = (float*)(w + OFF_XW0);
  float* xw1s  = (float*)(w + OFF_XW1);
  u16* seqkp   = (u16*)(w + OFF_SEQ);
  int* labs    = (int*)(w + OFF_LABS);
  u16* W0kp    = (u16*)(w + OFF_W0);
  u16* W1xkp   = (u16*)(w + OFF_W1X);
  u16* W1rkp   = (u16*)(w + OFF_W1R);
  u16* F0      = (u16*)(w + OFF_F0);
  u16* h0f     = (u16*)(w + OFF_H0F);
  u16* B0      = (u16*)(w + OFF_B0);
  u16* F1      = (u16*)(w + OFF_F1);
  u16* B1      = (u16*)(w + OFF_B1);

  init_zero<<<192, 256, 0, stream>>>(
      F0, F0 + (size_t)129 * SLOT16,
      B0 + (size_t)128 * SLOT64, B0 + (size_t)(129 + 128) * SLOT64,
      F1, F1 + (size_t)129 * SLOT64,
      B1 + (size_t)128 * SLOT64, B1 + (size_t)(129 + 128) * SLOT64, ctrs);

  build_seq<<<384, 256, 0, stream>>>(user, sysr, ulab, slab, seqkp, labs);

  cvt_w<<<dim3(1152, 12), 256, 0, stream>>>(postWhh0, priWhh0, postWih1, priWih1,
                                            postWhh1, priWhh1, W0kp, W1xkp, W1rkp);

  xw_gemm<<<dim3(48, 4), 256, 0, stream>>>(seqkp, postWih0, priWih0, postb0, prib0, xw0);

  {
    const u16* a0 = W0kp; const float* a1 = xw0;
    void* args[] = {(void*)&a0, (void*)&a1, (void*)&F0, (void*)&h0f, (void*)&B0, (void*)&ctrs};
    hipError_t e = hipLaunchCooperativeKernel((const void*)persistA_k, dim3(192), dim3(256),
                                              args, LDSA_BYTES, stream);
    if (e != hipSuccess)
      persistA_k<<<192, 256, LDSA_BYTES, stream>>>(W0kp, xw0, F0, h0f, B0, ctrs);
  }
  {
    const u16* a0 = W1xkp; const u16* a1 = W1rkp;
    const u16* a2 = h0f; const u16* a3 = B0;
    void* args[] = {(void*)&a0, (void*)&a1, (void*)&postWih1, (void*)&priWih1,
                    (void*)&postb1, (void*)&prib1, (void*)&a2, (void*)&a3,
                    (void*)&F1, (void*)&B1, (void*)&xw1s, (void*)&ctrs};
    hipError_t e = hipLaunchCooperativeKernel((const void*)persistB_k, dim3(192), dim3(256),
                                              args, LDSB_BYTES, stream);
    if (e != hipSuccess)
      persistB_k<<<192, 256, LDSB_BYTES, stream>>>(W1xkp, W1rkp, postWih1, priWih1,
                                                   postb1, prib1, h0f, B0, F1, B1, xw1s, ctrs);
  }

  em_k<<<4096, 256, 0, stream>>>(F1, B1, postPW, postPb, priPW, priPb, em);

  final_k<<<1, 64, 0, stream>>>(em, labs, trans, out);
}